// Round 18
// baseline (80.087 us; speedup 1.0000x reference)
//
#include <hip/hip_runtime.h>
#include <stdint.h>

// Problem constants (B=2, H=8, N=2048, D=64, f32 in/out).
#define B_ 2
#define H_ 8
#define N_ 2048
#define D_ 64
#define BH_ (B_ * H_)
#define NROWS (BH_ * N_)      // 32768
#define TPB_ 288              // tasks per bh: sum_{g2=0}^{63} ceil((2g2+2)/16)
#define TASKS (TPB_ * BH_)    // 4608 = 8 * 576
#define EPSF 8e-3f            // margin below which we re-resolve the row in f64
#define INFF __int_as_float(0x7f800000)

using u64 = unsigned long long;
using u32 = unsigned int;
typedef __attribute__((ext_vector_type(8))) short short8;   // 8 bf16
typedef __attribute__((ext_vector_type(4))) float f32x4;

#define MFMA16(A, B, C) __builtin_amdgcn_mfma_f32_16x16x32_bf16((A), (B), (C), 0, 0, 0)

// ---------------------------------------------------------------------------
// Prep (k only — the qfrag image was net-negative traffic; verbatim r7-r14,
// passed): split k into bf16 hi/lo in MFMA B-FRAGMENT layout
// [jg][h(2)][lane(64)][16B] so phase1 reads one fragment as a single
// coalesced 1KB global_load_dwordx4. Writer thread (row r, group kg):
// h = kg>>2, lane = (kg&3)*16 + (r&15). Also ksq[r]; zeroes count.
// ---------------------------------------------------------------------------
__global__ __launch_bounds__(256) void prep_k(
    const float* __restrict__ k, char* __restrict__ khi_g,
    char* __restrict__ klo_g, float* __restrict__ ksq_g,
    u32* __restrict__ count)
{
  if (blockIdx.x == 0 && threadIdx.x == 0) count[0] = 0;
  const int t = (int)blockIdx.x * 256 + threadIdx.x;  // NROWS*8 total
  const int r = t >> 3, kg = t & 7;
  const float* kp = k + (size_t)r * D_ + kg * 8;
  const float4 f0 = *(const float4*)kp;
  const float4 f1 = *(const float4*)(kp + 4);
  const float vv[8] = {f0.x, f0.y, f0.z, f0.w, f1.x, f1.y, f1.z, f1.w};
  u32 hw[4], lw[4];
  float ps = 0.f;
  #pragma unroll
  for (int e = 0; e < 4; ++e) {
    const float va = vv[2 * e], vb = vv[2 * e + 1];
    ps = fmaf(va, va, ps); ps = fmaf(vb, vb, ps);
    const u32 ha = __float_as_uint(va) & 0xFFFF0000u;
    const u32 hb = __float_as_uint(vb) & 0xFFFF0000u;
    hw[e] = (ha >> 16) | hb;
    const u32 la = __float_as_uint(va - __uint_as_float(ha));
    const u32 lb = __float_as_uint(vb - __uint_as_float(hb));
    lw[e] = (la >> 16) | (lb & 0xFFFF0000u);
  }
  const size_t off = ((size_t)(r >> 4) * 2 + (kg >> 2)) * 1024 +
                     (size_t)(((kg & 3) << 4) + (r & 15)) * 16;
  *(uint4*)(khi_g + off) = make_uint4(hw[0], hw[1], hw[2], hw[3]);
  *(uint4*)(klo_g + off) = make_uint4(lw[0], lw[1], lw[2], lw[3]);
  float ssum = ps;                                    // |k_row|^2
  ssum += __shfl_xor(ssum, 1);
  ssum += __shfl_xor(ssum, 2);
  ssum += __shfl_xor(ssum, 4);
  if (kg == 0) ksq_g[r] = ssum;
}

__device__ __forceinline__ void cvt_hilo(const float* p, short8& hi, short8& lo) {
  const float4 f0 = *(const float4*)p;
  const float4 f1 = *(const float4*)(p + 4);
  const float vv[8] = {f0.x, f0.y, f0.z, f0.w, f1.x, f1.y, f1.z, f1.w};
  #pragma unroll
  for (int e = 0; e < 8; ++e) {
    const float v = vv[e];
    const u32 hb = __float_as_uint(v) & 0xFFFF0000u;
    hi[e] = (short)(hb >> 16);
    lo[e] = (short)(__float_as_uint(v - __uint_as_float(hb)) >> 16);
  }
}

// ---------------------------------------------------------------------------
// Phase 1 (r15 structure with CH=16 decode; q converted IN-KERNEL per
// r9-r14's many-times-passed cvt_hilo into named regs — the qfrag image was
// neutral for phase1 and cost prep traffic). 1-wave tasks, direct k-fragment
// loads, split-bf16 3-term dot, float best/sec tracking, sortable-key u64
// cross-lane reduce (first-index ties == np.argmax). Per-(row,j) numerics
// BIT-IDENTICAL to r12-r17.
// ---------------------------------------------------------------------------
__global__ __launch_bounds__(64, 3) void phase1(
    const float* __restrict__ q, const char* __restrict__ khi_g,
    const char* __restrict__ klo_g, const float* __restrict__ ksq_g,
    u64* __restrict__ bestc, u32* __restrict__ secc)
{
  const int b = (int)blockIdx.x;
  const int task = (b & 7) * (TASKS / 8) + (b >> 3);  // XCD swizzle (bijective)
  const int bh = task / TPB_;
  int rem = task - bh * TPB_;
  int g2 = 0, nc = 1;                                 // nc(g2) = (2g2+17)>>4
  while (rem >= nc) { rem -= nc; ++g2; nc = (2 * g2 + 17) >> 4; }
  const int c = rem;
  const int jfirst = c * 16;
  const int jlast = min(jfirst + 15, 2 * g2 + 1);     // inclusive subtile idx

  const int lane = threadIdx.x & 63;
  const int grp = lane >> 4, c0 = lane & 15;
  const int i0 = g2 * 32;

  // ---- q: 2 named A-frag sets (rows i0 + {0,16} + c0), bf16 hi/lo ----
  short8 ah00, ah01, al00, al01, ah10, ah11, al10, al11;
  {
    const float* q0 = q + ((size_t)bh * N_ + i0 + c0) * D_ + grp * 8;
    cvt_hilo(q0, ah00, al00);
    cvt_hilo(q0 + 32, ah01, al01);
    const float* q1 = q0 + 16 * D_;
    cvt_hilo(q1, ah10, al10);
    cvt_hilo(q1 + 32, ah11, al11);
  }

  // ---- running best/sec over the chunk ----
  float bf[2][4], sf[2][4];
  u32 bj[2][4];
  #pragma unroll
  for (int s = 0; s < 2; ++s)
    #pragma unroll
    for (int r2 = 0; r2 < 4; ++r2) {
      bf[s][r2] = INFF; sf[s][r2] = INFF; bj[s][r2] = 0;
    }

  const size_t fb = (size_t)bh * 128 * 2048;          // 256KB per bh
  const char* ph = khi_g + fb + (size_t)jfirst * 2048 + lane * 16;
  const char* pl = klo_g + fb + (size_t)jfirst * 2048 + lane * 16;
  const float* pk = ksq_g + (size_t)bh * N_ + jfirst * 16 + c0;

  for (int js = jfirst; js <= jlast; ++js) {
    const short8 ch0 = *(const short8*)(ph);
    const short8 ch1 = *(const short8*)(ph + 1024);
    const short8 cl0 = *(const short8*)(pl);
    const short8 cl1 = *(const short8*)(pl + 1024);
    const float cks = *pk;
    ph += 2048; pl += 2048; pk += 16;

    const int jcol = js * 16 + c0;
    // ---- s = 0 (rows i0..i0+15) ----
    if (js <= 2 * g2) {
      const bool dsub = (js == 2 * g2);
      f32x4 aA = {0.f, 0.f, 0.f, 0.f}, aB = {0.f, 0.f, 0.f, 0.f};
      aA = MFMA16(ah00, ch0, aA);  aB = MFMA16(ah01, ch1, aB);
      aA = MFMA16(ah00, cl0, aA);  aB = MFMA16(ah01, cl1, aB);
      aA = MFMA16(al00, ch0, aA);  aB = MFMA16(al01, ch1, aB);
      #pragma unroll
      for (int reg = 0; reg < 4; ++reg) {
        float score = fmaf(-2.f, aA[reg] + aB[reg], cks);
        if (dsub && jcol > i0 + grp * 4 + reg) score = INFF;
        const float loser = fmaxf(bf[0][reg], score);
        sf[0][reg] = fminf(sf[0][reg], loser);
        if (score < bf[0][reg]) bj[0][reg] = (u32)jcol;
        bf[0][reg] = fminf(bf[0][reg], score);
      }
    }
    // ---- s = 1 (rows i0+16..i0+31); jlast <= 2g2+1 so always active ----
    {
      const bool dsub = (js == 2 * g2 + 1);
      f32x4 aA = {0.f, 0.f, 0.f, 0.f}, aB = {0.f, 0.f, 0.f, 0.f};
      aA = MFMA16(ah10, ch0, aA);  aB = MFMA16(ah11, ch1, aB);
      aA = MFMA16(ah10, cl0, aA);  aB = MFMA16(ah11, cl1, aB);
      aA = MFMA16(al10, ch0, aA);  aB = MFMA16(al11, ch1, aB);
      #pragma unroll
      for (int reg = 0; reg < 4; ++reg) {
        float score = fmaf(-2.f, aA[reg] + aB[reg], cks);
        if (dsub && jcol > i0 + 16 + grp * 4 + reg) score = INFF;
        const float loser = fmaxf(bf[1][reg], score);
        sf[1][reg] = fminf(sf[1][reg], loser);
        if (score < bf[1][reg]) bj[1][reg] = (u32)jcol;
        bf[1][reg] = fminf(bf[1][reg], score);
      }
    }
  }

  // ---- cross-lane reduce over the 16 col-slots; store one entry/row ----
  #pragma unroll
  for (int s = 0; s < 2; ++s) {
    #pragma unroll
    for (int reg = 0; reg < 4; ++reg) {
      const u32 bbits = __float_as_uint(bf[s][reg]);
      const u32 key = bbits ^ (u32)(((int)bbits >> 31) | 0x80000000);
      u64 pkk = ((u64)key << 32) | bj[s][reg];
      float sv = sf[s][reg];
      #pragma unroll
      for (int m = 1; m < 16; m <<= 1) {
        const u64 opk = (u64)__shfl_xor((long long)pkk, m);
        const float osv = __shfl_xor(sv, m);
        const u32 mk = (u32)(pkk >> 32), ok = (u32)(opk >> 32);
        const u32 lk = (opk < pkk) ? mk : ok;         // loser's key
        const u32 lb = (lk & 0x80000000u) ? (lk ^ 0x80000000u) : ~lk;
        sv = fminf(fminf(sv, osv), __uint_as_float(lb));
        if (opk < pkk) pkk = opk;
      }
      if (c0 == 0) {
        const size_t rr = (size_t)bh * N_ + i0 + s * 16 + grp * 4 + reg;
        bestc[(size_t)c * NROWS + rr] = pkk;
        secc[(size_t)c * NROWS + rr] = __float_as_uint(sv);
      }
    }
  }
}

// ---------------------------------------------------------------------------
// Combine + gather (verbatim r15-r17, passed): 4-way parallel chunk reduce +
// LDS merge (CH=16 nch); near-ties appended to compacted flaglist; gather
// with provisional output for flagged rows (overwritten by exact_fused).
// ---------------------------------------------------------------------------
__global__ __launch_bounds__(256) void combine_gather(
    const u64* __restrict__ bestc, const u32* __restrict__ secc,
    const float* __restrict__ v, float* __restrict__ out,
    u32* __restrict__ flaglist, u32* __restrict__ count)
{
  __shared__ u64 pk_s[4][64];
  __shared__ float s1_s[4][64];
  __shared__ u32 idx_s[64];
  const int tid = threadIdx.x;
  const int r0 = (int)blockIdx.x * 64;
  const int p = tid >> 6, t6 = tid & 63;

  {
    const int r = r0 + t6;
    const int i = r & (N_ - 1);
    const int nch = (2 * (i >> 5) + 17) >> 4;  // chunks covering this group
    u64 b0 = ~0ull;
    float bcur = INFF, s1 = INFF;
    int cstar = -1;
    for (int c2 = p; c2 < nch; c2 += 4) {
      const u64 kk = bestc[(size_t)c2 * NROWS + r];
      const u32 key = (u32)(kk >> 32);
      const u32 bits = (key & 0x80000000u) ? (key ^ 0x80000000u) : ~key;
      const float f = __uint_as_float(bits);
      if (kk < b0) { s1 = fminf(s1, bcur); b0 = kk; bcur = f; cstar = c2; }
      else s1 = fminf(s1, f);
    }
    if (cstar >= 0)
      s1 = fminf(s1, __uint_as_float(secc[(size_t)cstar * NROWS + r]));
    pk_s[p][t6] = b0;
    s1_s[p][t6] = s1;
  }
  __syncthreads();

  if (tid < 64) {
    u64 b0 = ~0ull;
    float bcur = INFF, s1 = INFF;
    #pragma unroll
    for (int pp = 0; pp < 4; ++pp) {
      const u64 kk = pk_s[pp][tid];
      const u32 key = (u32)(kk >> 32);
      const u32 bits = (key & 0x80000000u) ? (key ^ 0x80000000u) : ~key;
      const float f = __uint_as_float(bits);       // NaN for empty partial: ok
      if (kk < b0) { s1 = fminf(s1, bcur); b0 = kk; bcur = f; }
      else s1 = fminf(s1, f);                      // fminf(x, NaN) = x
      s1 = fminf(s1, s1_s[pp][tid]);
    }
    idx_s[tid] = (u32)(b0 & 0xFFFFu);
    if ((s1 - bcur) < EPSF) {                      // NaN-safe: INF-INF -> false
      const u32 pos = atomicAdd(count, 1u);
      flaglist[pos] = (u32)(r0 + tid);
    }
  }
  __syncthreads();

  #pragma unroll
  for (int iter = 0; iter < 4; ++iter) {
    const int tk = tid + iter * 256;
    const int rl = tk >> 4, cc = tk & 15;
    const int r = r0 + rl;
    const u32 j = idx_s[rl];
    const int bh = r >> 11;
    const float4 val = ((const float4*)(v + ((size_t)bh * N_ + j) * D_))[cc];
    ((float4*)(out + (size_t)r * D_))[cc] = val;
  }
}

// ---------------------------------------------------------------------------
// Exact f64 (fused): one 1024-thread block (16 waves) per flagged row;
// wave w scans j-slice [128w, 128w+127] with the VERBATIM r12-r17 slice
// body (lane-per-row scan + lexicographic (d2, j) 64-lane butterfly), LDS
// merge of the 16 slice winners (same lexicographic rule), direct v-write.
// Replaces exact_partial + exact_final (one fewer launch, no pd/pj
// round-trip); first-index tie semantics unchanged.
// ---------------------------------------------------------------------------
__global__ __launch_bounds__(1024) void exact_fused(
    const float* __restrict__ q, const float* __restrict__ k,
    const float* __restrict__ v, float* __restrict__ out,
    const u32* __restrict__ flaglist, const u32* __restrict__ count)
{
  __shared__ double sd[16];
  __shared__ int sj[16];
  const int tid = threadIdx.x;
  const int w = tid >> 6;              // slice index (wave id)
  const int lane = tid & 63;
  const int cnt = (int)count[0];
  for (int li = blockIdx.x; li < cnt; li += (int)gridDim.x) {
    const int r = (int)flaglist[li];
    const int bh = r >> 11;
    const int i = r & (N_ - 1);
    const int jbase = w * 128;

    double bbest = 1e300;
    int bjj = 0x7FFFFFFF;
    if (jbase <= i) {                  // wave-uniform
      const float4* qr = (const float4*)(q + (size_t)r * D_);
      float4 qv[16];
      #pragma unroll
      for (int t2 = 0; t2 < 16; ++t2) qv[t2] = qr[t2];
      double s0 = 0, s1 = 0, s2 = 0, s3 = 0;
      #pragma unroll
      for (int t2 = 0; t2 < 16; ++t2) {
        s0 = fma((double)qv[t2].x, (double)qv[t2].x, s0);
        s1 = fma((double)qv[t2].y, (double)qv[t2].y, s1);
        s2 = fma((double)qv[t2].z, (double)qv[t2].z, s2);
        s3 = fma((double)qv[t2].w, (double)qv[t2].w, s3);
      }
      const double qsqd = (s0 + s1) + (s2 + s3);
      const float* kb = k + (size_t)bh * N_ * D_;

      #pragma unroll
      for (int u = 0; u < 2; ++u) {
        const int j = jbase + u * 64 + lane;
        if (j <= i) {
          const float4* kr = (const float4*)(kb + (size_t)j * D_);
          double a0 = 0, a1 = 0, a2 = 0, a3 = 0;
          double t0 = 0, t1 = 0, t2d = 0, t3 = 0;
          #pragma unroll
          for (int t2 = 0; t2 < 16; ++t2) {
            const float4 kv = kr[t2];
            const double k0 = kv.x, k1 = kv.y, k2 = kv.z, k3 = kv.w;
            a0 = fma((double)qv[t2].x, k0, a0);
            a1 = fma((double)qv[t2].y, k1, a1);
            a2 = fma((double)qv[t2].z, k2, a2);
            a3 = fma((double)qv[t2].w, k3, a3);
            t0 = fma(k0, k0, t0);
            t1 = fma(k1, k1, t1);
            t2d = fma(k2, k2, t2d);
            t3 = fma(k3, k3, t3);
          }
          const double raw = (qsqd + ((t0 + t1) + (t2d + t3))) -
                             2.0 * ((a0 + a1) + (a2 + a3));
          const double d2 = raw > 0.0 ? raw : 0.0;
          if (d2 < bbest) { bbest = d2; bjj = j; }  // ascending j: first on tie
        }
      }
      #pragma unroll
      for (int m = 1; m < 64; m <<= 1) {
        const double ob = __shfl_xor(bbest, m);
        const int oj = __shfl_xor(bjj, m);
        if (ob < bbest || (ob == bbest && oj < bjj)) { bbest = ob; bjj = oj; }
      }
    }
    if (lane == 0) { sd[w] = bbest; sj[w] = bjj; }
    __syncthreads();

    if (w == 0) {                      // wave 0 merges the 16 slice winners
      double d = (lane < 16) ? sd[lane] : 1e300;
      int j = (lane < 16) ? sj[lane] : 0x7FFFFFFF;
      #pragma unroll
      for (int m = 1; m < 16; m <<= 1) {
        const double od = __shfl_xor(d, m);
        const int oj = __shfl_xor(j, m);
        if (od < d || (od == d && oj < j)) { d = od; j = oj; }
      }
      if (lane < 16) {                 // lanes 0-15 hold the winner
        const float4 val =
            ((const float4*)(v + ((size_t)bh * N_ + j) * D_))[lane];
        ((float4*)(out + (size_t)r * D_))[lane] = val;
      }
    }
    __syncthreads();
  }
}

// ---------------------------------------------------------------------------
extern "C" void kernel_launch(void* const* d_in, const int* in_sizes, int n_in,
                              void* d_out, int out_size, void* d_ws,
                              size_t ws_size, hipStream_t stream) {
  const float* q = (const float*)d_in[0];
  const float* k = (const float*)d_in[1];
  const float* v = (const float*)d_in[2];
  float* out = (float*)d_out;

  // ws layout (256 MiB available):
  // [0: count][4K: flaglist 128K][256K: ksq 128K][1M: khi 4M][8M: klo 4M]
  // [16M: bestc 2M][24M: secc 1M]
  char* ws = (char*)d_ws;
  u32* count = (u32*)ws;
  u32* flaglist = (u32*)(ws + 4096);
  float* ksq_g = (float*)(ws + 256 * 1024);
  char* khi_g = ws + 1ull * 1024 * 1024;
  char* klo_g = ws + 8ull * 1024 * 1024;
  u64* bestc = (u64*)(ws + 16ull * 1024 * 1024);
  u32* secc = (u32*)(ws + 24ull * 1024 * 1024);

  prep_k<<<(NROWS * 8) / 256, 256, 0, stream>>>(k, khi_g, klo_g, ksq_g, count);
  phase1<<<TASKS, 64, 0, stream>>>(q, khi_g, klo_g, ksq_g, bestc, secc);
  combine_gather<<<NROWS / 64, 256, 0, stream>>>(bestc, secc, v, out,
                                                 flaglist, count);
  exact_fused<<<256, 1024, 0, stream>>>(q, k, v, out, flaglist, count);
}

// Round 19
// 56.540 us; speedup vs baseline: 1.4165x; 1.4165x over previous
//
#include <hip/hip_runtime.h>
#include <stdint.h>

// Problem constants (B=2, H=8, N=2048, D=64, f32 in/out).
#define B_ 2
#define H_ 8
#define N_ 2048
#define D_ 64
#define BH_ (B_ * H_)
#define NROWS (BH_ * N_)      // 32768
#define TPB_ 288              // tasks per bh: sum_{g2=0}^{63} ceil((2g2+2)/16)
#define TASKS (TPB_ * BH_)    // 4608 = 8 * 576
#define EPSF 8e-3f            // margin below which we re-resolve the row in f64
#define INFF __int_as_float(0x7f800000)

using u64 = unsigned long long;
using u32 = unsigned int;
typedef __attribute__((ext_vector_type(8))) short short8;   // 8 bf16
typedef __attribute__((ext_vector_type(4))) float f32x4;

#define MFMA16(A, B, C) __builtin_amdgcn_mfma_f32_16x16x32_bf16((A), (B), (C), 0, 0, 0)

// ---------------------------------------------------------------------------
// Prep (verbatim r18, passed lineage r7-r17): split k into bf16 hi/lo in MFMA
// B-FRAGMENT layout [jg][h(2)][lane(64)][16B]; ksq[r]; zeroes count.
// ---------------------------------------------------------------------------
__global__ __launch_bounds__(256) void prep_k(
    const float* __restrict__ k, char* __restrict__ khi_g,
    char* __restrict__ klo_g, float* __restrict__ ksq_g,
    u32* __restrict__ count)
{
  if (blockIdx.x == 0 && threadIdx.x == 0) count[0] = 0;
  const int t = (int)blockIdx.x * 256 + threadIdx.x;  // NROWS*8 total
  const int r = t >> 3, kg = t & 7;
  const float* kp = k + (size_t)r * D_ + kg * 8;
  const float4 f0 = *(const float4*)kp;
  const float4 f1 = *(const float4*)(kp + 4);
  const float vv[8] = {f0.x, f0.y, f0.z, f0.w, f1.x, f1.y, f1.z, f1.w};
  u32 hw[4], lw[4];
  float ps = 0.f;
  #pragma unroll
  for (int e = 0; e < 4; ++e) {
    const float va = vv[2 * e], vb = vv[2 * e + 1];
    ps = fmaf(va, va, ps); ps = fmaf(vb, vb, ps);
    const u32 ha = __float_as_uint(va) & 0xFFFF0000u;
    const u32 hb = __float_as_uint(vb) & 0xFFFF0000u;
    hw[e] = (ha >> 16) | hb;
    const u32 la = __float_as_uint(va - __uint_as_float(ha));
    const u32 lb = __float_as_uint(vb - __uint_as_float(hb));
    lw[e] = (la >> 16) | (lb & 0xFFFF0000u);
  }
  const size_t off = ((size_t)(r >> 4) * 2 + (kg >> 2)) * 1024 +
                     (size_t)(((kg & 3) << 4) + (r & 15)) * 16;
  *(uint4*)(khi_g + off) = make_uint4(hw[0], hw[1], hw[2], hw[3]);
  *(uint4*)(klo_g + off) = make_uint4(lw[0], lw[1], lw[2], lw[3]);
  float ssum = ps;                                    // |k_row|^2
  ssum += __shfl_xor(ssum, 1);
  ssum += __shfl_xor(ssum, 2);
  ssum += __shfl_xor(ssum, 4);
  if (kg == 0) ksq_g[r] = ssum;
}

__device__ __forceinline__ void cvt_hilo(const float* p, short8& hi, short8& lo) {
  const float4 f0 = *(const float4*)p;
  const float4 f1 = *(const float4*)(p + 4);
  const float vv[8] = {f0.x, f0.y, f0.z, f0.w, f1.x, f1.y, f1.z, f1.w};
  #pragma unroll
  for (int e = 0; e < 8; ++e) {
    const float v = vv[e];
    const u32 hb = __float_as_uint(v) & 0xFFFF0000u;
    hi[e] = (short)(hb >> 16);
    lo[e] = (short)(__float_as_uint(v - __uint_as_float(hb)) >> 16);
  }
}

// ---------------------------------------------------------------------------
// Phase 1 (verbatim r18, which is the r12 dataflow + CH=16 decode; passed):
// 1-wave tasks, in-kernel q cvt into named regs, direct k-fragment loads,
// split-bf16 3-term dot, float best/sec tracking, sortable-key u64 reduce
// (first-index ties == np.argmax).
// ---------------------------------------------------------------------------
__global__ __launch_bounds__(64, 3) void phase1(
    const float* __restrict__ q, const char* __restrict__ khi_g,
    const char* __restrict__ klo_g, const float* __restrict__ ksq_g,
    u64* __restrict__ bestc, u32* __restrict__ secc)
{
  const int b = (int)blockIdx.x;
  const int task = (b & 7) * (TASKS / 8) + (b >> 3);  // XCD swizzle (bijective)
  const int bh = task / TPB_;
  int rem = task - bh * TPB_;
  int g2 = 0, nc = 1;                                 // nc(g2) = (2g2+17)>>4
  while (rem >= nc) { rem -= nc; ++g2; nc = (2 * g2 + 17) >> 4; }
  const int c = rem;
  const int jfirst = c * 16;
  const int jlast = min(jfirst + 15, 2 * g2 + 1);     // inclusive subtile idx

  const int lane = threadIdx.x & 63;
  const int grp = lane >> 4, c0 = lane & 15;
  const int i0 = g2 * 32;

  // ---- q: 2 named A-frag sets (rows i0 + {0,16} + c0), bf16 hi/lo ----
  short8 ah00, ah01, al00, al01, ah10, ah11, al10, al11;
  {
    const float* q0 = q + ((size_t)bh * N_ + i0 + c0) * D_ + grp * 8;
    cvt_hilo(q0, ah00, al00);
    cvt_hilo(q0 + 32, ah01, al01);
    const float* q1 = q0 + 16 * D_;
    cvt_hilo(q1, ah10, al10);
    cvt_hilo(q1 + 32, ah11, al11);
  }

  // ---- running best/sec over the chunk ----
  float bf[2][4], sf[2][4];
  u32 bj[2][4];
  #pragma unroll
  for (int s = 0; s < 2; ++s)
    #pragma unroll
    for (int r2 = 0; r2 < 4; ++r2) {
      bf[s][r2] = INFF; sf[s][r2] = INFF; bj[s][r2] = 0;
    }

  const size_t fb = (size_t)bh * 128 * 2048;          // 256KB per bh
  const char* ph = khi_g + fb + (size_t)jfirst * 2048 + lane * 16;
  const char* pl = klo_g + fb + (size_t)jfirst * 2048 + lane * 16;
  const float* pk = ksq_g + (size_t)bh * N_ + jfirst * 16 + c0;

  for (int js = jfirst; js <= jlast; ++js) {
    const short8 ch0 = *(const short8*)(ph);
    const short8 ch1 = *(const short8*)(ph + 1024);
    const short8 cl0 = *(const short8*)(pl);
    const short8 cl1 = *(const short8*)(pl + 1024);
    const float cks = *pk;
    ph += 2048; pl += 2048; pk += 16;

    const int jcol = js * 16 + c0;
    // ---- s = 0 (rows i0..i0+15) ----
    if (js <= 2 * g2) {
      const bool dsub = (js == 2 * g2);
      f32x4 aA = {0.f, 0.f, 0.f, 0.f}, aB = {0.f, 0.f, 0.f, 0.f};
      aA = MFMA16(ah00, ch0, aA);  aB = MFMA16(ah01, ch1, aB);
      aA = MFMA16(ah00, cl0, aA);  aB = MFMA16(ah01, cl1, aB);
      aA = MFMA16(al00, ch0, aA);  aB = MFMA16(al01, ch1, aB);
      #pragma unroll
      for (int reg = 0; reg < 4; ++reg) {
        float score = fmaf(-2.f, aA[reg] + aB[reg], cks);
        if (dsub && jcol > i0 + grp * 4 + reg) score = INFF;
        const float loser = fmaxf(bf[0][reg], score);
        sf[0][reg] = fminf(sf[0][reg], loser);
        if (score < bf[0][reg]) bj[0][reg] = (u32)jcol;
        bf[0][reg] = fminf(bf[0][reg], score);
      }
    }
    // ---- s = 1 (rows i0+16..i0+31); jlast <= 2g2+1 so always active ----
    {
      const bool dsub = (js == 2 * g2 + 1);
      f32x4 aA = {0.f, 0.f, 0.f, 0.f}, aB = {0.f, 0.f, 0.f, 0.f};
      aA = MFMA16(ah10, ch0, aA);  aB = MFMA16(ah11, ch1, aB);
      aA = MFMA16(ah10, cl0, aA);  aB = MFMA16(ah11, cl1, aB);
      aA = MFMA16(al10, ch0, aA);  aB = MFMA16(al11, ch1, aB);
      #pragma unroll
      for (int reg = 0; reg < 4; ++reg) {
        float score = fmaf(-2.f, aA[reg] + aB[reg], cks);
        if (dsub && jcol > i0 + 16 + grp * 4 + reg) score = INFF;
        const float loser = fmaxf(bf[1][reg], score);
        sf[1][reg] = fminf(sf[1][reg], loser);
        if (score < bf[1][reg]) bj[1][reg] = (u32)jcol;
        bf[1][reg] = fminf(bf[1][reg], score);
      }
    }
  }

  // ---- cross-lane reduce over the 16 col-slots; store one entry/row ----
  #pragma unroll
  for (int s = 0; s < 2; ++s) {
    #pragma unroll
    for (int reg = 0; reg < 4; ++reg) {
      const u32 bbits = __float_as_uint(bf[s][reg]);
      const u32 key = bbits ^ (u32)(((int)bbits >> 31) | 0x80000000);
      u64 pkk = ((u64)key << 32) | bj[s][reg];
      float sv = sf[s][reg];
      #pragma unroll
      for (int m = 1; m < 16; m <<= 1) {
        const u64 opk = (u64)__shfl_xor((long long)pkk, m);
        const float osv = __shfl_xor(sv, m);
        const u32 mk = (u32)(pkk >> 32), ok = (u32)(opk >> 32);
        const u32 lk = (opk < pkk) ? mk : ok;         // loser's key
        const u32 lb = (lk & 0x80000000u) ? (lk ^ 0x80000000u) : ~lk;
        sv = fminf(fminf(sv, osv), __uint_as_float(lb));
        if (opk < pkk) pkk = opk;
      }
      if (c0 == 0) {
        const size_t rr = (size_t)bh * N_ + i0 + s * 16 + grp * 4 + reg;
        bestc[(size_t)c * NROWS + rr] = pkk;
        secc[(size_t)c * NROWS + rr] = __float_as_uint(sv);
      }
    }
  }
}

// ---------------------------------------------------------------------------
// Combine + gather (verbatim r15-r18, passed): 4-way parallel chunk reduce +
// LDS merge (CH=16 nch); near-ties appended to compacted flaglist; gather
// with provisional output for flagged rows (overwritten by exact_final).
// ---------------------------------------------------------------------------
__global__ __launch_bounds__(256) void combine_gather(
    const u64* __restrict__ bestc, const u32* __restrict__ secc,
    const float* __restrict__ v, float* __restrict__ out,
    u32* __restrict__ flaglist, u32* __restrict__ count)
{
  __shared__ u64 pk_s[4][64];
  __shared__ float s1_s[4][64];
  __shared__ u32 idx_s[64];
  const int tid = threadIdx.x;
  const int r0 = (int)blockIdx.x * 64;
  const int p = tid >> 6, t6 = tid & 63;

  {
    const int r = r0 + t6;
    const int i = r & (N_ - 1);
    const int nch = (2 * (i >> 5) + 17) >> 4;  // chunks covering this group
    u64 b0 = ~0ull;
    float bcur = INFF, s1 = INFF;
    int cstar = -1;
    for (int c2 = p; c2 < nch; c2 += 4) {
      const u64 kk = bestc[(size_t)c2 * NROWS + r];
      const u32 key = (u32)(kk >> 32);
      const u32 bits = (key & 0x80000000u) ? (key ^ 0x80000000u) : ~key;
      const float f = __uint_as_float(bits);
      if (kk < b0) { s1 = fminf(s1, bcur); b0 = kk; bcur = f; cstar = c2; }
      else s1 = fminf(s1, f);
    }
    if (cstar >= 0)
      s1 = fminf(s1, __uint_as_float(secc[(size_t)cstar * NROWS + r]));
    pk_s[p][t6] = b0;
    s1_s[p][t6] = s1;
  }
  __syncthreads();

  if (tid < 64) {
    u64 b0 = ~0ull;
    float bcur = INFF, s1 = INFF;
    #pragma unroll
    for (int pp = 0; pp < 4; ++pp) {
      const u64 kk = pk_s[pp][tid];
      const u32 key = (u32)(kk >> 32);
      const u32 bits = (key & 0x80000000u) ? (key ^ 0x80000000u) : ~key;
      const float f = __uint_as_float(bits);       // NaN for empty partial: ok
      if (kk < b0) { s1 = fminf(s1, bcur); b0 = kk; bcur = f; }
      else s1 = fminf(s1, f);                      // fminf(x, NaN) = x
      s1 = fminf(s1, s1_s[pp][tid]);
    }
    idx_s[tid] = (u32)(b0 & 0xFFFFu);
    if ((s1 - bcur) < EPSF) {                      // NaN-safe: INF-INF -> false
      const u32 pos = atomicAdd(count, 1u);
      flaglist[pos] = (u32)(r0 + tid);
    }
  }
  __syncthreads();

  #pragma unroll
  for (int iter = 0; iter < 4; ++iter) {
    const int tk = tid + iter * 256;
    const int rl = tk >> 4, cc = tk & 15;
    const int r = r0 + rl;
    const u32 j = idx_s[rl];
    const int bh = r >> 11;
    const float4 val = ((const float4*)(v + ((size_t)bh * N_ + j) * D_))[cc];
    ((float4*)(out + (size_t)r * D_))[cc] = val;
  }
}

// ---------------------------------------------------------------------------
// Exact f64 stage A (verbatim r12-r17, passed 6x): task = (flagged row,
// 128-row j-slice); one INDEPENDENT 64-thr block per task (any CU — this is
// what r18's fusion broke); lexicographic (d2, j) wave reduce -> partial.
// ---------------------------------------------------------------------------
__global__ __launch_bounds__(64) void exact_partial(
    const float* __restrict__ q, const float* __restrict__ k,
    const u32* __restrict__ flaglist, const u32* __restrict__ count,
    double* __restrict__ pd, int* __restrict__ pj)
{
  const int lane = threadIdx.x & 63;
  const int cnt = (int)count[0];
  for (int t = blockIdx.x; (t >> 4) < cnt; t += (int)gridDim.x) {
    const int li = t >> 4, slice = t & 15;
    const int r = (int)flaglist[li];
    const int bh = r >> 11;
    const int i = r & (N_ - 1);
    const int jbase = slice * 128;

    double bbest = 1e300;
    int bjj = 0x7FFFFFFF;
    if (jbase <= i) {
      const float4* qr = (const float4*)(q + (size_t)r * D_);
      float4 qv[16];
      #pragma unroll
      for (int t2 = 0; t2 < 16; ++t2) qv[t2] = qr[t2];
      double s0 = 0, s1 = 0, s2 = 0, s3 = 0;
      #pragma unroll
      for (int t2 = 0; t2 < 16; ++t2) {
        s0 = fma((double)qv[t2].x, (double)qv[t2].x, s0);
        s1 = fma((double)qv[t2].y, (double)qv[t2].y, s1);
        s2 = fma((double)qv[t2].z, (double)qv[t2].z, s2);
        s3 = fma((double)qv[t2].w, (double)qv[t2].w, s3);
      }
      const double qsqd = (s0 + s1) + (s2 + s3);
      const float* kb = k + (size_t)bh * N_ * D_;

      #pragma unroll
      for (int u = 0; u < 2; ++u) {
        const int j = jbase + u * 64 + lane;
        if (j <= i) {
          const float4* kr = (const float4*)(kb + (size_t)j * D_);
          double a0 = 0, a1 = 0, a2 = 0, a3 = 0;
          double t0 = 0, t1 = 0, t2d = 0, t3 = 0;
          #pragma unroll
          for (int t2 = 0; t2 < 16; ++t2) {
            const float4 kv = kr[t2];
            const double k0 = kv.x, k1 = kv.y, k2 = kv.z, k3 = kv.w;
            a0 = fma((double)qv[t2].x, k0, a0);
            a1 = fma((double)qv[t2].y, k1, a1);
            a2 = fma((double)qv[t2].z, k2, a2);
            a3 = fma((double)qv[t2].w, k3, a3);
            t0 = fma(k0, k0, t0);
            t1 = fma(k1, k1, t1);
            t2d = fma(k2, k2, t2d);
            t3 = fma(k3, k3, t3);
          }
          const double raw = (qsqd + ((t0 + t1) + (t2d + t3))) -
                             2.0 * ((a0 + a1) + (a2 + a3));
          const double d2 = raw > 0.0 ? raw : 0.0;
          if (d2 < bbest) { bbest = d2; bjj = j; }  // ascending j: first on tie
        }
      }
      #pragma unroll
      for (int m = 1; m < 64; m <<= 1) {
        const double ob = __shfl_xor(bbest, m);
        const int oj = __shfl_xor(bjj, m);
        if (ob < bbest || (ob == bbest && oj < bjj)) { bbest = ob; bjj = oj; }
      }
    }
    if (lane == 0) {
      pd[(size_t)li * 16 + slice] = bbest;
      pj[(size_t)li * 16 + slice] = bjj;
    }
  }
}

// ---------------------------------------------------------------------------
// Exact f64 stage B (verbatim r12-r17, passed 6x): reduce 16 slice partials,
// write the winning v row to out.
// ---------------------------------------------------------------------------
__global__ __launch_bounds__(64) void exact_final(
    const double* __restrict__ pd, const int* __restrict__ pj,
    const u32* __restrict__ flaglist, const u32* __restrict__ count,
    const float* __restrict__ v, float* __restrict__ out)
{
  const int lane = threadIdx.x & 63;
  const int cnt = (int)count[0];
  for (int li = blockIdx.x; li < cnt; li += (int)gridDim.x) {
    const int r = (int)flaglist[li];
    const int bh = r >> 11;
    double d = (lane < 16) ? pd[(size_t)li * 16 + lane] : 1e300;
    int j = (lane < 16) ? pj[(size_t)li * 16 + lane] : 0x7FFFFFFF;
    #pragma unroll
    for (int m = 1; m < 16; m <<= 1) {   // reduces within each 16-lane group
      const double od = __shfl_xor(d, m);
      const int oj = __shfl_xor(j, m);
      if (od < d || (od == d && oj < j)) { d = od; j = oj; }
    }
    if (lane < 16) {                     // lanes 0-15 hold the winner
      const float4 val =
          ((const float4*)(v + ((size_t)bh * N_ + j) * D_))[lane];
      ((float4*)(out + (size_t)r * D_))[lane] = val;
    }
  }
}

// ---------------------------------------------------------------------------
extern "C" void kernel_launch(void* const* d_in, const int* in_sizes, int n_in,
                              void* d_out, int out_size, void* d_ws,
                              size_t ws_size, hipStream_t stream) {
  const float* q = (const float*)d_in[0];
  const float* k = (const float*)d_in[1];
  const float* v = (const float*)d_in[2];
  float* out = (float*)d_out;

  // ws layout (256 MiB available):
  // [0: count][4K: flaglist 128K][256K: ksq 128K][1M: khi 4M][8M: klo 4M]
  // [16M: bestc 2M][24M: secc 1M][32M: pd 4M][40M: pj 2M]
  char* ws = (char*)d_ws;
  u32* count = (u32*)ws;
  u32* flaglist = (u32*)(ws + 4096);
  float* ksq_g = (float*)(ws + 256 * 1024);
  char* khi_g = ws + 1ull * 1024 * 1024;
  char* klo_g = ws + 8ull * 1024 * 1024;
  u64* bestc = (u64*)(ws + 16ull * 1024 * 1024);
  u32* secc = (u32*)(ws + 24ull * 1024 * 1024);
  double* pd = (double*)(ws + 32ull * 1024 * 1024);
  int* pj = (int*)(ws + 40ull * 1024 * 1024);

  prep_k<<<(NROWS * 8) / 256, 256, 0, stream>>>(k, khi_g, klo_g, ksq_g, count);
  phase1<<<TASKS, 64, 0, stream>>>(q, khi_g, klo_g, ksq_g, bestc, secc);
  combine_gather<<<NROWS / 64, 256, 0, stream>>>(bestc, secc, v, out,
                                                 flaglist, count);
  exact_partial<<<2048, 64, 0, stream>>>(q, k, flaglist, count, pd, pj);
  exact_final<<<256, 64, 0, stream>>>(pd, pj, flaglist, count, v, out);
}

// Round 20
// 53.984 us; speedup vs baseline: 1.4835x; 1.0474x over previous
//
#include <hip/hip_runtime.h>
#include <stdint.h>

// Problem constants (B=2, H=8, N=2048, D=64, f32 in/out).
#define B_ 2
#define H_ 8
#define N_ 2048
#define D_ 64
#define BH_ (B_ * H_)
#define NROWS (BH_ * N_)      // 32768
#define TPB_ 576              // tasks per bh: sum_{g1=0}^{127} ceil((g1+1)/16)
#define TASKS (TPB_ * BH_)    // 9216 = 8 * 1152
#define EPSF 8e-3f            // margin below which we re-resolve the row in f64
#define INFF __int_as_float(0x7f800000)

using u64 = unsigned long long;
using u32 = unsigned int;
typedef __attribute__((ext_vector_type(8))) short short8;   // 8 bf16
typedef __attribute__((ext_vector_type(4))) float f32x4;

#define MFMA16(A, B, C) __builtin_amdgcn_mfma_f32_16x16x32_bf16((A), (B), (C), 0, 0, 0)

// ---------------------------------------------------------------------------
// Prep (verbatim r7-r19, passed): split k into bf16 hi/lo in MFMA B-FRAGMENT
// layout [jg][h(2)][lane(64)][16B]; ksq[r]; zeroes count.
// ---------------------------------------------------------------------------
__global__ __launch_bounds__(256) void prep_k(
    const float* __restrict__ k, char* __restrict__ khi_g,
    char* __restrict__ klo_g, float* __restrict__ ksq_g,
    u32* __restrict__ count)
{
  if (blockIdx.x == 0 && threadIdx.x == 0) count[0] = 0;
  const int t = (int)blockIdx.x * 256 + threadIdx.x;  // NROWS*8 total
  const int r = t >> 3, kg = t & 7;
  const float* kp = k + (size_t)r * D_ + kg * 8;
  const float4 f0 = *(const float4*)kp;
  const float4 f1 = *(const float4*)(kp + 4);
  const float vv[8] = {f0.x, f0.y, f0.z, f0.w, f1.x, f1.y, f1.z, f1.w};
  u32 hw[4], lw[4];
  float ps = 0.f;
  #pragma unroll
  for (int e = 0; e < 4; ++e) {
    const float va = vv[2 * e], vb = vv[2 * e + 1];
    ps = fmaf(va, va, ps); ps = fmaf(vb, vb, ps);
    const u32 ha = __float_as_uint(va) & 0xFFFF0000u;
    const u32 hb = __float_as_uint(vb) & 0xFFFF0000u;
    hw[e] = (ha >> 16) | hb;
    const u32 la = __float_as_uint(va - __uint_as_float(ha));
    const u32 lb = __float_as_uint(vb - __uint_as_float(hb));
    lw[e] = (la >> 16) | (lb & 0xFFFF0000u);
  }
  const size_t off = ((size_t)(r >> 4) * 2 + (kg >> 2)) * 1024 +
                     (size_t)(((kg & 3) << 4) + (r & 15)) * 16;
  *(uint4*)(khi_g + off) = make_uint4(hw[0], hw[1], hw[2], hw[3]);
  *(uint4*)(klo_g + off) = make_uint4(lw[0], lw[1], lw[2], lw[3]);
  float ssum = ps;                                    // |k_row|^2
  ssum += __shfl_xor(ssum, 1);
  ssum += __shfl_xor(ssum, 2);
  ssum += __shfl_xor(ssum, 4);
  if (kg == 0) ksq_g[r] = ssum;
}

__device__ __forceinline__ void cvt_hilo(const float* p, short8& hi, short8& lo) {
  const float4 f0 = *(const float4*)p;
  const float4 f1 = *(const float4*)(p + 4);
  const float vv[8] = {f0.x, f0.y, f0.z, f0.w, f1.x, f1.y, f1.z, f1.w};
  #pragma unroll
  for (int e = 0; e < 8; ++e) {
    const float v = vv[e];
    const u32 hb = __float_as_uint(v) & 0xFFFF0000u;
    hi[e] = (short)(hb >> 16);
    lo[e] = (short)(__float_as_uint(v - __uint_as_float(hb)) >> 16);
  }
}

// ---------------------------------------------------------------------------
// Phase 1: THIN-WAVE variant — task = (bh, 16-ROW group g1, chunk of <=16
// subtiles). One A-frag set (16 VGPR) + one tracking set: live regs ~70 ->
// launch_bounds(64,6) fits 6 waves/SIMD (vs 1.5-2 measured before), trading
// 2x L2 fragment traffic (~528MB, working set 1MB/XCD = L2-resident) for
// 3-4x latency-hiding residency. 9216 tasks = 9 waves/SIMD queue.
// Per-(row,j) numerics BIT-IDENTICAL to r12-r19 (same split-bf16 3-term dot,
// same 6-MFMA order per visit, ascending-j scan, float best/sec tracking,
// sortable-key u64 reduce, first-index ties == np.argmax). Diagonal subtile
// for rows [16g1,16g1+15] is js == g1. Chunk index c <= 7.
// ---------------------------------------------------------------------------
__global__ __launch_bounds__(64, 6) void phase1(
    const float* __restrict__ q, const char* __restrict__ khi_g,
    const char* __restrict__ klo_g, const float* __restrict__ ksq_g,
    u64* __restrict__ bestc, u32* __restrict__ secc)
{
  const int b = (int)blockIdx.x;
  const int task = (b & 7) * (TASKS / 8) + (b >> 3);  // XCD swizzle (bijective)
  const int bh = task / TPB_;
  const int rem = task - bh * TPB_;
  // block m covers groups [16m,16m+15], m+1 chunks each; cum = 8m(m+1)
  int m = 0;
  while (8 * (m + 1) * (m + 2) <= rem) ++m;           // m in 0..7
  const int idx = rem - 8 * m * (m + 1);
  const int qn = idx / (m + 1);
  const int g1 = 16 * m + qn;
  const int c = idx - qn * (m + 1);
  const int jfirst = c * 16;
  const int jlast = min(jfirst + 15, g1);             // inclusive subtile idx

  const int lane = threadIdx.x & 63;
  const int grp = lane >> 4, c0 = lane & 15;
  const int i0 = g1 * 16;

  // ---- q: 1 A-frag set (rows i0 + c0), bf16 hi/lo, in-kernel ----
  short8 ah0, ah1, al0, al1;
  {
    const float* q0 = q + ((size_t)bh * N_ + i0 + c0) * D_ + grp * 8;
    cvt_hilo(q0, ah0, al0);
    cvt_hilo(q0 + 32, ah1, al1);
  }

  // ---- running best/sec over the chunk ----
  float bf[4], sf[4];
  u32 bj[4];
  #pragma unroll
  for (int r2 = 0; r2 < 4; ++r2) {
    bf[r2] = INFF; sf[r2] = INFF; bj[r2] = 0;
  }

  const size_t fb = (size_t)bh * 128 * 2048;          // 256KB per bh
  const char* ph = khi_g + fb + (size_t)jfirst * 2048 + lane * 16;
  const char* pl = klo_g + fb + (size_t)jfirst * 2048 + lane * 16;
  const float* pk = ksq_g + (size_t)bh * N_ + jfirst * 16 + c0;

  for (int js = jfirst; js <= jlast; ++js) {
    const short8 ch0 = *(const short8*)(ph);
    const short8 ch1 = *(const short8*)(ph + 1024);
    const short8 cl0 = *(const short8*)(pl);
    const short8 cl1 = *(const short8*)(pl + 1024);
    const float cks = *pk;
    ph += 2048; pl += 2048; pk += 16;

    const int jcol = js * 16 + c0;
    const bool dsub = (js == g1);                     // diagonal subtile
    f32x4 aA = {0.f, 0.f, 0.f, 0.f}, aB = {0.f, 0.f, 0.f, 0.f};
    aA = MFMA16(ah0, ch0, aA);  aB = MFMA16(ah1, ch1, aB);
    aA = MFMA16(ah0, cl0, aA);  aB = MFMA16(ah1, cl1, aB);
    aA = MFMA16(al0, ch0, aA);  aB = MFMA16(al1, ch1, aB);
    #pragma unroll
    for (int reg = 0; reg < 4; ++reg) {
      float score = fmaf(-2.f, aA[reg] + aB[reg], cks);
      if (dsub && jcol > i0 + grp * 4 + reg) score = INFF;
      const float loser = fmaxf(bf[reg], score);
      sf[reg] = fminf(sf[reg], loser);
      if (score < bf[reg]) bj[reg] = (u32)jcol;
      bf[reg] = fminf(bf[reg], score);
    }
  }

  // ---- cross-lane reduce over the 16 col-slots; store one entry/row ----
  #pragma unroll
  for (int reg = 0; reg < 4; ++reg) {
    const u32 bbits = __float_as_uint(bf[reg]);
    const u32 key = bbits ^ (u32)(((int)bbits >> 31) | 0x80000000);
    u64 pkk = ((u64)key << 32) | bj[reg];
    float sv = sf[reg];
    #pragma unroll
    for (int mm = 1; mm < 16; mm <<= 1) {
      const u64 opk = (u64)__shfl_xor((long long)pkk, mm);
      const float osv = __shfl_xor(sv, mm);
      const u32 mk = (u32)(pkk >> 32), ok = (u32)(opk >> 32);
      const u32 lk = (opk < pkk) ? mk : ok;           // loser's key
      const u32 lb = (lk & 0x80000000u) ? (lk ^ 0x80000000u) : ~lk;
      sv = fminf(fminf(sv, osv), __uint_as_float(lb));
      if (opk < pkk) pkk = opk;
    }
    if (c0 == 0) {
      const size_t rr = (size_t)bh * N_ + i0 + grp * 4 + reg;
      bestc[(size_t)c * NROWS + rr] = pkk;
      secc[(size_t)c * NROWS + rr] = __float_as_uint(sv);
    }
  }
}

// ---------------------------------------------------------------------------
// Combine + gather (r15-r19 structure, passed; nch updated for 16-row
// groups): 4-way parallel chunk reduce + LDS merge; near-ties appended to
// compacted flaglist; gather with provisional output for flagged rows
// (overwritten by exact_final).
// ---------------------------------------------------------------------------
__global__ __launch_bounds__(256) void combine_gather(
    const u64* __restrict__ bestc, const u32* __restrict__ secc,
    const float* __restrict__ v, float* __restrict__ out,
    u32* __restrict__ flaglist, u32* __restrict__ count)
{
  __shared__ u64 pk_s[4][64];
  __shared__ float s1_s[4][64];
  __shared__ u32 idx_s[64];
  const int tid = threadIdx.x;
  const int r0 = (int)blockIdx.x * 64;
  const int p = tid >> 6, t6 = tid & 63;

  {
    const int r = r0 + t6;
    const int i = r & (N_ - 1);
    const int nch = ((i >> 4) + 16) >> 4;      // chunks covering this group
    u64 b0 = ~0ull;
    float bcur = INFF, s1 = INFF;
    int cstar = -1;
    for (int c2 = p; c2 < nch; c2 += 4) {
      const u64 kk = bestc[(size_t)c2 * NROWS + r];
      const u32 key = (u32)(kk >> 32);
      const u32 bits = (key & 0x80000000u) ? (key ^ 0x80000000u) : ~key;
      const float f = __uint_as_float(bits);
      if (kk < b0) { s1 = fminf(s1, bcur); b0 = kk; bcur = f; cstar = c2; }
      else s1 = fminf(s1, f);
    }
    if (cstar >= 0)
      s1 = fminf(s1, __uint_as_float(secc[(size_t)cstar * NROWS + r]));
    pk_s[p][t6] = b0;
    s1_s[p][t6] = s1;
  }
  __syncthreads();

  if (tid < 64) {
    u64 b0 = ~0ull;
    float bcur = INFF, s1 = INFF;
    #pragma unroll
    for (int pp = 0; pp < 4; ++pp) {
      const u64 kk = pk_s[pp][tid];
      const u32 key = (u32)(kk >> 32);
      const u32 bits = (key & 0x80000000u) ? (key ^ 0x80000000u) : ~key;
      const float f = __uint_as_float(bits);       // NaN for empty partial: ok
      if (kk < b0) { s1 = fminf(s1, bcur); b0 = kk; bcur = f; }
      else s1 = fminf(s1, f);                      // fminf(x, NaN) = x
      s1 = fminf(s1, s1_s[pp][tid]);
    }
    idx_s[tid] = (u32)(b0 & 0xFFFFu);
    if ((s1 - bcur) < EPSF) {                      // NaN-safe: INF-INF -> false
      const u32 pos = atomicAdd(count, 1u);
      flaglist[pos] = (u32)(r0 + tid);
    }
  }
  __syncthreads();

  #pragma unroll
  for (int iter = 0; iter < 4; ++iter) {
    const int tk = tid + iter * 256;
    const int rl = tk >> 4, cc = tk & 15;
    const int r = r0 + rl;
    const u32 j = idx_s[rl];
    const int bh = r >> 11;
    const float4 val = ((const float4*)(v + ((size_t)bh * N_ + j) * D_))[cc];
    ((float4*)(out + (size_t)r * D_))[cc] = val;
  }
}

// ---------------------------------------------------------------------------
// Exact f64 stage A (verbatim r12-r19, passed 7x): task = (flagged row,
// 128-row j-slice); one INDEPENDENT 64-thr block per task; lexicographic
// (d2, j) wave reduce -> partial.
// ---------------------------------------------------------------------------
__global__ __launch_bounds__(64) void exact_partial(
    const float* __restrict__ q, const float* __restrict__ k,
    const u32* __restrict__ flaglist, const u32* __restrict__ count,
    double* __restrict__ pd, int* __restrict__ pj)
{
  const int lane = threadIdx.x & 63;
  const int cnt = (int)count[0];
  for (int t = blockIdx.x; (t >> 4) < cnt; t += (int)gridDim.x) {
    const int li = t >> 4, slice = t & 15;
    const int r = (int)flaglist[li];
    const int bh = r >> 11;
    const int i = r & (N_ - 1);
    const int jbase = slice * 128;

    double bbest = 1e300;
    int bjj = 0x7FFFFFFF;
    if (jbase <= i) {
      const float4* qr = (const float4*)(q + (size_t)r * D_);
      float4 qv[16];
      #pragma unroll
      for (int t2 = 0; t2 < 16; ++t2) qv[t2] = qr[t2];
      double s0 = 0, s1 = 0, s2 = 0, s3 = 0;
      #pragma unroll
      for (int t2 = 0; t2 < 16; ++t2) {
        s0 = fma((double)qv[t2].x, (double)qv[t2].x, s0);
        s1 = fma((double)qv[t2].y, (double)qv[t2].y, s1);
        s2 = fma((double)qv[t2].z, (double)qv[t2].z, s2);
        s3 = fma((double)qv[t2].w, (double)qv[t2].w, s3);
      }
      const double qsqd = (s0 + s1) + (s2 + s3);
      const float* kb = k + (size_t)bh * N_ * D_;

      #pragma unroll
      for (int u = 0; u < 2; ++u) {
        const int j = jbase + u * 64 + lane;
        if (j <= i) {
          const float4* kr = (const float4*)(kb + (size_t)j * D_);
          double a0 = 0, a1 = 0, a2 = 0, a3 = 0;
          double t0 = 0, t1 = 0, t2d = 0, t3 = 0;
          #pragma unroll
          for (int t2 = 0; t2 < 16; ++t2) {
            const float4 kv = kr[t2];
            const double k0 = kv.x, k1 = kv.y, k2 = kv.z, k3 = kv.w;
            a0 = fma((double)qv[t2].x, k0, a0);
            a1 = fma((double)qv[t2].y, k1, a1);
            a2 = fma((double)qv[t2].z, k2, a2);
            a3 = fma((double)qv[t2].w, k3, a3);
            t0 = fma(k0, k0, t0);
            t1 = fma(k1, k1, t1);
            t2d = fma(k2, k2, t2d);
            t3 = fma(k3, k3, t3);
          }
          const double raw = (qsqd + ((t0 + t1) + (t2d + t3))) -
                             2.0 * ((a0 + a1) + (a2 + a3));
          const double d2 = raw > 0.0 ? raw : 0.0;
          if (d2 < bbest) { bbest = d2; bjj = j; }  // ascending j: first on tie
        }
      }
      #pragma unroll
      for (int mm = 1; mm < 64; mm <<= 1) {
        const double ob = __shfl_xor(bbest, mm);
        const int oj = __shfl_xor(bjj, mm);
        if (ob < bbest || (ob == bbest && oj < bjj)) { bbest = ob; bjj = oj; }
      }
    }
    if (lane == 0) {
      pd[(size_t)li * 16 + slice] = bbest;
      pj[(size_t)li * 16 + slice] = bjj;
    }
  }
}

// ---------------------------------------------------------------------------
// Exact f64 stage B (verbatim r12-r19, passed 7x): reduce 16 slice partials,
// write the winning v row to out.
// ---------------------------------------------------------------------------
__global__ __launch_bounds__(64) void exact_final(
    const double* __restrict__ pd, const int* __restrict__ pj,
    const u32* __restrict__ flaglist, const u32* __restrict__ count,
    const float* __restrict__ v, float* __restrict__ out)
{
  const int lane = threadIdx.x & 63;
  const int cnt = (int)count[0];
  for (int li = blockIdx.x; li < cnt; li += (int)gridDim.x) {
    const int r = (int)flaglist[li];
    const int bh = r >> 11;
    double d = (lane < 16) ? pd[(size_t)li * 16 + lane] : 1e300;
    int j = (lane < 16) ? pj[(size_t)li * 16 + lane] : 0x7FFFFFFF;
    #pragma unroll
    for (int mm = 1; mm < 16; mm <<= 1) {  // reduces within each 16-lane group
      const double od = __shfl_xor(d, mm);
      const int oj = __shfl_xor(j, mm);
      if (od < d || (od == d && oj < j)) { d = od; j = oj; }
    }
    if (lane < 16) {                       // lanes 0-15 hold the winner
      const float4 val =
          ((const float4*)(v + ((size_t)bh * N_ + j) * D_))[lane];
      ((float4*)(out + (size_t)r * D_))[lane] = val;
    }
  }
}

// ---------------------------------------------------------------------------
extern "C" void kernel_launch(void* const* d_in, const int* in_sizes, int n_in,
                              void* d_out, int out_size, void* d_ws,
                              size_t ws_size, hipStream_t stream) {
  const float* q = (const float*)d_in[0];
  const float* k = (const float*)d_in[1];
  const float* v = (const float*)d_in[2];
  float* out = (float*)d_out;

  // ws layout (256 MiB available):
  // [0: count][4K: flaglist 128K][256K: ksq 128K][1M: khi 4M][8M: klo 4M]
  // [16M: bestc 2M][24M: secc 1M][32M: pd 4M][40M: pj 2M]
  char* ws = (char*)d_ws;
  u32* count = (u32*)ws;
  u32* flaglist = (u32*)(ws + 4096);
  float* ksq_g = (float*)(ws + 256 * 1024);
  char* khi_g = ws + 1ull * 1024 * 1024;
  char* klo_g = ws + 8ull * 1024 * 1024;
  u64* bestc = (u64*)(ws + 16ull * 1024 * 1024);
  u32* secc = (u32*)(ws + 24ull * 1024 * 1024);
  double* pd = (double*)(ws + 32ull * 1024 * 1024);
  int* pj = (int*)(ws + 40ull * 1024 * 1024);

  prep_k<<<(NROWS * 8) / 256, 256, 0, stream>>>(k, khi_g, klo_g, ksq_g, count);
  phase1<<<TASKS, 64, 0, stream>>>(q, khi_g, klo_g, ksq_g, bestc, secc);
  combine_gather<<<NROWS / 64, 256, 0, stream>>>(bestc, secc, v, out,
                                                 flaglist, count);
  exact_partial<<<2048, 64, 0, stream>>>(q, k, flaglist, count, pd, pj);
  exact_final<<<256, 64, 0, stream>>>(pd, pj, flaglist, count, v, out);
}